// Round 5
// baseline (1028.830 us; speedup 1.0000x reference)
//
#include <hip/hip_runtime.h>
#include <math.h>

#define TT 2048

typedef __attribute__((ext_vector_type(8))) short bfrag;   // 8 bf16 in 4 VGPRs
typedef __attribute__((ext_vector_type(4))) short sh4;     // 4 bf16 (b64)
typedef __attribute__((ext_vector_type(4))) float facc;    // 4 fp32 acc

#define NEG_BIG (-1.0e30f)

typedef __attribute__((address_space(1))) const void gas_void;
typedef __attribute__((address_space(3))) void las_void;

__device__ __forceinline__ void gl_lds16(const void* g, void* l) {
    __builtin_amdgcn_global_load_lds((gas_void*)g, (las_void*)l, 16, 0, 0);
}

__device__ __forceinline__ unsigned short f2b(float f) {
    union { float f; unsigned int i; } v; v.f = f;
    unsigned int b = v.i;
    return (unsigned short)((b + 0x7FFFu + ((b >> 16) & 1u)) >> 16);  // RNE
}
__device__ __forceinline__ void cvt8_f32(const float* __restrict__ p, unsigned short* d) {
    float4 lo = *(const float4*)p, hi = *(const float4*)(p + 4);
    d[0] = f2b(lo.x); d[1] = f2b(lo.y); d[2] = f2b(lo.z); d[3] = f2b(lo.w);
    d[4] = f2b(hi.x); d[5] = f2b(hi.y); d[6] = f2b(hi.z); d[7] = f2b(hi.w);
}

// ---------------------------------------------------------------------------
// fp32 -> bf16 flat convert (n8 = count of 8-element chunks)
// ---------------------------------------------------------------------------
__global__ __launch_bounds__(256) void k_cvt(const float* __restrict__ in,
                                             unsigned short* __restrict__ out, int n8) {
    int c = blockIdx.x * 256 + threadIdx.x;
    if (c < n8) {
        unsigned short t[8];
        cvt8_f32(in + (size_t)c * 8, t);
        *(uint4*)(out + (size_t)c * 8) = *(const uint4*)t;
    }
}

// ---------------------------------------------------------------------------
// Weight transpose+convert: W (2048 x N fp32) -> WT (N x 2048 bf16)
// ---------------------------------------------------------------------------
__global__ __launch_bounds__(256) void k_wt(const float* __restrict__ W,
                                            unsigned short* __restrict__ WT, int N) {
    __shared__ alignas(16) unsigned short tile[64][72];
    int r0 = blockIdx.y * 64, c0 = blockIdx.x * 64;
    int tid = threadIdx.x;
    for (int i = 0; i < 2; ++i) {
        int c = tid + i * 256;
        int row = c >> 3, c8 = (c & 7) * 8;
        unsigned short t[8];
        cvt8_f32(W + (size_t)(r0 + row) * N + c0 + c8, t);
        *(uint4*)&tile[row][c8] = *(const uint4*)t;
    }
    __syncthreads();
    for (int i = 0; i < 2; ++i) {
        int c = tid + i * 256;
        int col = c >> 3, r8 = (c & 7) * 8;
        unsigned short t[8];
        for (int j = 0; j < 8; ++j) t[j] = tile[r8 + j][col];
        *(uint4*)(WT + (size_t)(c0 + col) * 2048 + r0 + r8) = *(const uint4*)t;
    }
}

// ---------------------------------------------------------------------------
// V transpose: KV (8192 x 1024 bf16, V = cols 512..1023) -> VbT (512 x 8192)
// ---------------------------------------------------------------------------
__global__ __launch_bounds__(256) void k_vt(const unsigned short* __restrict__ KV,
                                            unsigned short* __restrict__ VbT) {
    __shared__ alignas(16) unsigned short tile[64][72];
    int r0 = blockIdx.y * 64, c0 = blockIdx.x * 64;
    int tid = threadIdx.x;
    for (int i = 0; i < 2; ++i) {
        int c = tid + i * 256;
        int row = c >> 3, c8 = (c & 7) * 8;
        *(uint4*)&tile[row][c8] =
            *(const uint4*)(KV + (size_t)(r0 + row) * 1024 + 512 + c0 + c8);
    }
    __syncthreads();
    for (int i = 0; i < 2; ++i) {
        int c = tid + i * 256;
        int col = c >> 3, r8 = (c & 7) * 8;
        unsigned short t[8];
        for (int j = 0; j < 8; ++j) t[j] = tile[r8 + j][col];
        *(uint4*)(VbT + (size_t)(c0 + col) * 8192 + r0 + r8) = *(const uint4*)t;
    }
}

// ---------------------------------------------------------------------------
// m97-style GEMM: C (MxN) = A (MxK bf16) @ Bt^T (Bt: NxK bf16).
// 128x128 tile, BK=32, global_load_lds width=16, XOR chunk swizzle,
// coalesced LDS-staged epilogue; outF=1 -> fp32 out, else bf16.
// ---------------------------------------------------------------------------
__global__ __launch_bounds__(256) void k_gemm_bt(const unsigned short* __restrict__ A,
                                                 const unsigned short* __restrict__ Bt,
                                                 void* __restrict__ Cmat,
                                                 int M, int N, int K, int outF) {
    __shared__ union SM {
        struct { unsigned short A[128][32]; unsigned short B[128][32]; } s;  // 16 KB
        unsigned short ct[32][136];
        float          ctf[32][136];
    } sm;
    int tid = threadIdx.x;
    int w = tid >> 6, lane = tid & 63, quad = lane >> 4, l15 = lane & 15;
    int m0 = blockIdx.y * 128, n0 = blockIdx.x * 128;
    int wm = (w >> 1) * 64, wn = (w & 1) * 64;

    int srow   = lane >> 2;
    int schunk = (lane & 3) ^ ((lane >> 3) & 3);
    int rslot  = (quad ^ ((l15 >> 1) & 3)) * 8;

    facc acc[4][4];
    for (int mi = 0; mi < 4; ++mi)
        for (int ni = 0; ni < 4; ++ni)
            for (int r = 0; r < 4; ++r) acc[mi][ni][r] = 0.f;

    for (int k0 = 0; k0 < K; k0 += 32) {
        for (int j = 0; j < 2; ++j) {
            int row = w * 32 + j * 16 + srow;
            gl_lds16(A  + (size_t)(m0 + row) * K + k0 + schunk * 8, &sm.s.A[w * 32 + j * 16][0]);
            gl_lds16(Bt + (size_t)(n0 + row) * K + k0 + schunk * 8, &sm.s.B[w * 32 + j * 16][0]);
        }
        __syncthreads();
        bfrag af[4], bf[4];
        for (int mi = 0; mi < 4; ++mi) af[mi] = *(const bfrag*)&sm.s.A[wm + mi * 16 + l15][rslot];
        for (int ni = 0; ni < 4; ++ni) bf[ni] = *(const bfrag*)&sm.s.B[wn + ni * 16 + l15][rslot];
        for (int mi = 0; mi < 4; ++mi)
            for (int ni = 0; ni < 4; ++ni)
                acc[mi][ni] = __builtin_amdgcn_mfma_f32_16x16x32_bf16(af[mi], bf[ni], acc[mi][ni], 0, 0, 0);
        __syncthreads();
    }

    for (int t = 0; t < 4; ++t) {
        __syncthreads();
        for (int ni = 0; ni < 4; ++ni)
            for (int r = 0; r < 4; ++r) {
                int lr = (w >> 1) * 16 + quad * 4 + r;
                int lc = wn + ni * 16 + l15;
                if (outF) sm.ctf[lr][lc] = acc[t][ni][r];
                else      sm.ct [lr][lc] = f2b(acc[t][ni][r]);
            }
        __syncthreads();
        if (outF) {
            for (int i = 0; i < 4; ++i) {
                int cc = tid + i * 256;
                int lr = cc >> 5, c4 = (cc & 31) * 4;
                int grow = m0 + (lr >> 4) * 64 + t * 16 + (lr & 15);
                *(float4*)((float*)Cmat + (size_t)grow * N + n0 + c4) =
                    *(const float4*)&sm.ctf[lr][c4];
            }
        } else {
            for (int i = 0; i < 2; ++i) {
                int cc = tid + i * 256;
                int lr = cc >> 4, c8 = (cc & 15) * 8;
                int grow = m0 + (lr >> 4) * 64 + t * 16 + (lr & 15);
                *(uint4*)((unsigned short*)Cmat + (size_t)grow * N + n0 + c8) =
                    *(const uint4*)&sm.ct[lr][c8];
            }
        }
    }
}

// ---------------------------------------------------------------------------
// RoPE in-place on bf16 X (8192 rows, stride elems/row, nh heads of 128).
// ---------------------------------------------------------------------------
__global__ __launch_bounds__(256) void k_rope(unsigned short* __restrict__ X,
                                              int lognh, int stride,
                                              const int* __restrict__ posPtr) {
    int tid = blockIdx.x * 256 + threadIdx.x;
    int d = tid & 63;
    int nh = 1 << lognh;
    int h = (tid >> 6) & (nh - 1);
    int row = tid >> (6 + lognh);
    int t = row & (TT - 1);
    float p = (float)(*posPtr + t);
    size_t base = (size_t)row * stride + h * 128 + d;
    union { unsigned int i; float f; } a, b2;
    a.i  = ((unsigned int)X[base]) << 16;
    b2.i = ((unsigned int)X[base + 64]) << 16;
    float x1 = a.f, x2 = b2.f;
    int i1 = d >> 1;
    float f1 = exp2f(-(float)i1 * 0.20762050595278f);
    float f2 = exp2f(-(float)(i1 + 32) * 0.20762050595278f);
    float th1 = p * f1, th2 = p * f2;
    X[base]      = f2b(x1 * cosf(th1) - x2 * sinf(th1));
    X[base + 64] = f2b(x2 * cosf(th2) + x1 * sinf(th2));
}

// ---------------------------------------------------------------------------
// Flash attention v2 — S^T formulation. Causal, GQA (16q/4kv). Grid (16, 64),
// heavy-first (qt = 15 - blockIdx.x). Q-tile 128 (4 waves x 32 q), KT=64.
//   S^T = K·Q^T  : A-frag = K rows (LDS), B-frag = Q rows (registers).
//     C-layout: col(l15)=q, row(quad*4+r)=kpos → softmax stats = 2 shfl_xor.
//   O^T = V^T·P^T: A-frag = V^T rows (LDS), B-frag = P^T rows (LDS, written
//     as packed b64 from the S^T C-layout — no scalar scatter).
// All LDS tiles in m97 [rows][32] sub-buffer layout, staged by global_load_lds.
// 2 barriers/step. In-place att==Q (block-disjoint slices).
// ---------------------------------------------------------------------------
__global__ __launch_bounds__(256) void k_flash(const unsigned short* __restrict__ Q,
                                               const unsigned short* __restrict__ KV,
                                               const unsigned short* __restrict__ VbT,
                                               unsigned short* __restrict__ att) {
    __shared__ union SM {
        struct {
            unsigned short Ks[4][64][32];    // d-chunk kc: [kpos][d&31]   16 KB
            unsigned short Vt[2][128][32];   // kpos-chunk s: [d][kpos&31] 16 KB
            unsigned short Ps[4][2][32][32]; // wave, kpos-chunk: [q][kpos&31] 16 KB
        } s;
        unsigned short Osm[4][32][136];      // epilogue restage (35 KB)
    } sm;
    int tid = threadIdx.x;
    int w = tid >> 6, lane = tid & 63, quad = lane >> 4, l15 = lane & 15;
    int b = blockIdx.y >> 4, h = blockIdx.y & 15, kvh = h >> 2;
    int qt = (int)(gridDim.x - 1) - (int)blockIdx.x;   // heavy-first
    int qbase = qt * 128;

    // Q fragments (registers): lane l15 = q-row, quad*8+j over d
    bfrag qf[2][4];
    for (int g = 0; g < 2; ++g) {
        size_t qrow = (size_t)(b * TT + qbase + w * 32 + g * 16 + l15);
        for (int kc = 0; kc < 4; ++kc)
            qf[g][kc] = *(const bfrag*)(Q + qrow * 2048 + h * 128 + kc * 32 + quad * 8);
    }
    float mrow[2] = {NEG_BIG, NEG_BIG}, lrow[2] = {0.f, 0.f};
    facc o[2][8];
    for (int g = 0; g < 2; ++g)
        for (int sub = 0; sub < 8; ++sub)
            for (int r = 0; r < 4; ++r) o[g][sub][r] = 0.f;

    const float l2sc = 0.08838834764831845f * 1.44269504088896f;  // /sqrt(128)*log2e
    int srow = lane >> 2, schunk = lane & 3;

    for (int k0 = 0; k0 < qbase + 128; k0 += 64) {
        // ---- stage K (4 subs x 4 grps) and V^T (2 subs x 8 grps): 8 per wave
        for (int t = 0; t < 4; ++t) {
            int idx = w * 4 + t;                    // 0..15
            int ksub = idx >> 2, kgrp = idx & 3;
            gl_lds16(KV + (size_t)(b * TT + k0 + kgrp * 16 + srow) * 1024
                        + kvh * 128 + ksub * 32 + schunk * 8,
                     &sm.s.Ks[ksub][kgrp * 16][0]);
            int vsub = idx >> 3, vgrp = idx & 7;
            gl_lds16(VbT + (size_t)(kvh * 128 + vgrp * 16 + srow) * 8192
                         + b * TT + k0 + vsub * 32 + schunk * 8,
                     &sm.s.Vt[vsub][vgrp * 16][0]);
        }
        __syncthreads();

        // ---- S^T = K·Q^T : s[g][ks], 16 LDS loads, 32 MFMAs
        facc s[2][4];
        for (int g = 0; g < 2; ++g)
            for (int ks = 0; ks < 4; ++ks)
                for (int r = 0; r < 4; ++r) s[g][ks][r] = 0.f;
        for (int ks = 0; ks < 4; ++ks)
            for (int kc = 0; kc < 4; ++kc) {
                bfrag kf = *(const bfrag*)&sm.s.Ks[kc][ks * 16 + l15][quad * 8];
                s[0][ks] = __builtin_amdgcn_mfma_f32_16x16x32_bf16(kf, qf[0][kc], s[0][ks], 0, 0, 0);
                s[1][ks] = __builtin_amdgcn_mfma_f32_16x16x32_bf16(kf, qf[1][kc], s[1][ks], 0, 0, 0);
            }

        // ---- online softmax (per lane: q-col = g*16+l15; kpos = ks*16+quad*4+r)
        for (int g = 0; g < 2; ++g) {
            int qg = qbase + w * 32 + g * 16 + l15;
            float mx = NEG_BIG;
            for (int ks = 0; ks < 4; ++ks)
                for (int r = 0; r < 4; ++r) {
                    int kp = k0 + ks * 16 + quad * 4 + r;
                    float vv = (kp > qg) ? NEG_BIG : s[g][ks][r] * l2sc;
                    mx = fmaxf(mx, vv);
                }
            mx = fmaxf(mx, __shfl_xor(mx, 16, 64));
            mx = fmaxf(mx, __shfl_xor(mx, 32, 64));
            float mnew = fmaxf(mrow[g], mx);
            float alpha = exp2f(mrow[g] - mnew);
            float ps = 0.f;
            for (int ks = 0; ks < 4; ++ks) {
                unsigned short pb[4];
                for (int r = 0; r < 4; ++r) {
                    int kp = k0 + ks * 16 + quad * 4 + r;
                    float p = (kp > qg) ? 0.f : exp2f(s[g][ks][r] * l2sc - mnew);
                    ps += p;
                    pb[r] = f2b(p);
                }
                *(sh4*)&sm.s.Ps[w][ks >> 1][g * 16 + l15][(ks & 1) * 16 + quad * 4] =
                    *(const sh4*)pb;
            }
            ps += __shfl_xor(ps, 16, 64);
            ps += __shfl_xor(ps, 32, 64);
            lrow[g] = lrow[g] * alpha + ps;
            mrow[g] = mnew;
            for (int sub = 0; sub < 8; ++sub)
                for (int r = 0; r < 4; ++r) o[g][sub][r] *= alpha;
        }
        asm volatile("s_waitcnt lgkmcnt(0)" ::: "memory");  // wave-local Ps RAW

        // ---- O^T += V^T·P^T : 20 LDS loads, 32 MFMAs
        bfrag pf[2][2];
        for (int g = 0; g < 2; ++g)
            for (int ssub = 0; ssub < 2; ++ssub)
                pf[g][ssub] = *(const bfrag*)&sm.s.Ps[w][ssub][g * 16 + l15][quad * 8];
        for (int sub = 0; sub < 8; ++sub)
            for (int ssub = 0; ssub < 2; ++ssub) {
                bfrag vf = *(const bfrag*)&sm.s.Vt[ssub][sub * 16 + l15][quad * 8];
                o[0][sub] = __builtin_amdgcn_mfma_f32_16x16x32_bf16(vf, pf[0][ssub], o[0][sub], 0, 0, 0);
                o[1][sub] = __builtin_amdgcn_mfma_f32_16x16x32_bf16(vf, pf[1][ssub], o[1][sub], 0, 0, 0);
            }
        __syncthreads();
    }

    // ---- epilogue: O^T (col=q=l15, row=d=sub*16+quad*4+r) -> LDS -> coalesced
    for (int g = 0; g < 2; ++g) {
        float rl = 1.0f / lrow[g];
        for (int sub = 0; sub < 8; ++sub) {
            unsigned short ob[4];
            for (int r = 0; r < 4; ++r) ob[r] = f2b(o[g][sub][r] * rl);
            *(sh4*)&sm.Osm[w][g * 16 + l15][sub * 16 + quad * 4] = *(const sh4*)ob;
        }
    }
    asm volatile("s_waitcnt lgkmcnt(0)" ::: "memory");      // wave-local Osm RAW
    for (int i = 0; i < 8; ++i) {
        int idx = i * 64 + lane;                 // 512 chunks: 32 rows x 16
        int row = idx >> 4, ch = idx & 15;
        uint4 vv = *(const uint4*)&sm.Osm[w][row][ch * 8];
        *(uint4*)(att + (size_t)(b * TT + qbase + w * 32 + row) * 2048 + h * 128 + ch * 8) = vv;
    }
}

// ---------------------------------------------------------------------------
extern "C" void kernel_launch(void* const* d_in, const int* in_sizes, int n_in,
                              void* d_out, int out_size, void* d_ws, size_t ws_size,
                              hipStream_t stream) {
    const float* x  = (const float*)d_in[0];
    const float* Wq = (const float*)d_in[1];
    const float* Wk = (const float*)d_in[2];
    const float* Wv = (const float*)d_in[3];
    const float* Wo = (const float*)d_in[4];
    const int* pos  = (const int*)d_in[5];

    char* ws = (char*)d_ws;
    unsigned short* xb   = (unsigned short*)(ws + 0);          // 32 MB (8192x2048)
    unsigned short* Qb   = (unsigned short*)(ws + 33554432);   // 32 MB (8192x2048)
    unsigned short* KVb  = (unsigned short*)(ws + 67108864);   // 16 MB (8192x1024)
    unsigned short* VbT  = (unsigned short*)(ws + 83886080);   //  8 MB (512x8192)
    unsigned short* WqT  = (unsigned short*)(ws + 92274688);   //  8 MB (2048x2048)
    unsigned short* WkvT = (unsigned short*)(ws + 100663296);  //  4 MB (1024x2048)
    unsigned short* WoT  = (unsigned short*)(ws + 104857600);  //  8 MB -> 108 MB

    k_cvt<<<8192, 256, 0, stream>>>(x, xb, 2097152);
    k_wt<<<dim3(32, 32), 256, 0, stream>>>(Wq, WqT, 2048);
    k_wt<<<dim3(8, 32),  256, 0, stream>>>(Wk, WkvT, 512);
    k_wt<<<dim3(8, 32),  256, 0, stream>>>(Wv, WkvT + (size_t)512 * 2048, 512);
    k_wt<<<dim3(32, 32), 256, 0, stream>>>(Wo, WoT, 2048);

    k_gemm_bt<<<dim3(16, 64), 256, 0, stream>>>(xb, WqT,  Qb,  8192, 2048, 2048, 0);
    k_gemm_bt<<<dim3(8, 64),  256, 0, stream>>>(xb, WkvT, KVb, 8192, 1024, 2048, 0);

    k_rope<<<32768, 256, 0, stream>>>(Qb,  4, 2048, pos);
    k_rope<<<8192,  256, 0, stream>>>(KVb, 2, 1024, pos);

    k_vt<<<dim3(8, 128), 256, 0, stream>>>(KVb, VbT);

    k_flash<<<dim3(16, 64), 256, 0, stream>>>(Qb, KVb, VbT, Qb);

    k_gemm_bt<<<dim3(16, 64), 256, 0, stream>>>(Qb, WoT, d_out, 8192, 2048, 2048, 1);
}